// Round 1
// baseline (1045.656 us; speedup 1.0000x reference)
//
#include <hip/hip_runtime.h>

typedef unsigned short u16;
typedef __attribute__((ext_vector_type(8))) short sv8;   // 8 bf16 in 4 VGPRs
typedef __attribute__((ext_vector_type(4))) float fv4;   // MFMA accumulator

__device__ __forceinline__ u16 f2b(float x) {
    union { float f; unsigned u; } a; a.f = x;
    unsigned r = a.u + 0x7FFFu + ((a.u >> 16) & 1u);
    return (u16)(r >> 16);
}
__device__ __forceinline__ float b2f(u16 h) {
    union { unsigned u; float f; } a; a.u = ((unsigned)h) << 16;
    return a.f;
}

// ---------------------------------------------------------------------------
// GEMM: C[M,F] = A[M,K] @ W[K,F] + bias, W pre-transposed as Wt[F][K] (bf16).
// A is f32 (AF32) or bf16. Output f32 or bf16, optional relu epilogue.
// Block: 256 thr = 4 waves; tile 64x64, BK=32; wave w does rows w*16..w*16+15.
// mfma_f32_16x16x32_bf16 layouts (measured, learn_hip m89/m91):
//   A: lane holds row (l&15), k = (l>>4)*8 + j
//   B: lane holds col (l&15), k = (l>>4)*8 + j
//   D: col = l&15, row = (l>>4)*4 + r
// ---------------------------------------------------------------------------
template<bool AF32, bool OF32, bool RELU>
__global__ __launch_bounds__(256) void k_gemm(
    const void* __restrict__ Aptr, const u16* __restrict__ Wt,
    const float* __restrict__ bias, void* __restrict__ Cptr,
    int M, int K, int F)
{
    __shared__ u16 As[64][40];   // padded: stride 80B -> ~2-way bank alias (free)
    __shared__ u16 Bs[64][40];
    const int t = threadIdx.x;
    const int w = t >> 6;
    const int l = t & 63;
    const int m0 = blockIdx.x * 64;
    const int n0 = blockIdx.y * 64;
    const int arow = t >> 2;            // 0..63
    const int acol = (t & 3) << 3;      // 0,8,16,24

    fv4 acc[4] = {};

    for (int k0 = 0; k0 < K; k0 += 32) {
        sv8 av = {};
        const int gr = m0 + arow;
        if (gr < M) {
            if constexpr (AF32) {
                const fv4* Ap = (const fv4*)((const float*)Aptr + (size_t)gr * K + (k0 + acol));
                fv4 u = Ap[0], v = Ap[1];
                #pragma unroll
                for (int j = 0; j < 4; ++j) {
                    av[j]     = (short)f2b(u[j]);
                    av[j + 4] = (short)f2b(v[j]);
                }
            } else {
                av = *(const sv8*)((const u16*)Aptr + (size_t)gr * K + (k0 + acol));
            }
        }
        *(sv8*)&As[arow][acol] = av;
        *(sv8*)&Bs[arow][acol] = *(const sv8*)(Wt + (size_t)(n0 + arow) * K + (k0 + acol));
        __syncthreads();

        sv8 a = *(const sv8*)&As[(w << 4) + (l & 15)][(l >> 4) << 3];
        #pragma unroll
        for (int ct = 0; ct < 4; ++ct) {
            sv8 b = *(const sv8*)&Bs[(ct << 4) + (l & 15)][(l >> 4) << 3];
            acc[ct] = __builtin_amdgcn_mfma_f32_16x16x32_bf16(a, b, acc[ct], 0, 0, 0);
        }
        __syncthreads();
    }

    const int r0 = m0 + (w << 4) + ((l >> 4) << 2);
    #pragma unroll
    for (int ct = 0; ct < 4; ++ct) {
        const int col = n0 + (ct << 4) + (l & 15);
        const float bv = bias[col];
        #pragma unroll
        for (int r = 0; r < 4; ++r) {
            const int row = r0 + r;
            if (row < M) {
                float v = acc[ct][r] + bv;
                if constexpr (RELU) v = fmaxf(v, 0.f);
                if constexpr (OF32) ((float*)Cptr)[(size_t)row * F + col] = v;
                else                ((u16*)Cptr)[(size_t)row * F + col] = f2b(v);
            }
        }
    }
}

// --------------------------- CSR build (by dst) ----------------------------
__global__ void k_hist(const int* __restrict__ dst, int* __restrict__ counts, int E) {
    int i = blockIdx.x * 256 + threadIdx.x;
    if (i < E) atomicAdd(&counts[dst[i]], 1);
}

__global__ __launch_bounds__(1024) void k_scan(
    const int* __restrict__ counts, int* __restrict__ indptr,
    int* __restrict__ cursors, int n)
{
    __shared__ int sm[1024];
    const int t = threadIdx.x;
    const int CH = (n + 1023) >> 10;
    const int base = t * CH;
    int s = 0;
    for (int i = 0; i < CH; ++i) { int idx = base + i; if (idx < n) s += counts[idx]; }
    sm[t] = s;
    __syncthreads();
    for (int off = 1; off < 1024; off <<= 1) {
        int v = (t >= off) ? sm[t - off] : 0;
        __syncthreads();
        sm[t] += v;
        __syncthreads();
    }
    int run = sm[t] - s;   // exclusive prefix of this thread's chunk
    for (int i = 0; i < CH; ++i) {
        int idx = base + i;
        if (idx < n) { indptr[idx] = run; cursors[idx] = run; run += counts[idx]; }
    }
    if (t == 1023) indptr[n] = sm[1023];
}

__global__ void k_scatter(const int* __restrict__ dst, int* __restrict__ cursors,
                          int* __restrict__ eidx, int E) {
    int i = blockIdx.x * 256 + threadIdx.x;
    if (i < E) { int p = atomicAdd(&cursors[dst[i]], 1); eidx[p] = i; }
}

// ------------------- softmax aggregation (online, per node) ----------------
template<int F>
__global__ void k_agg(const u16* __restrict__ h16, const u16* __restrict__ eb16,
                      const u16* __restrict__ hd16, const int* __restrict__ srcs,
                      const int* __restrict__ indptr, const int* __restrict__ eidx,
                      u16* __restrict__ out16)
{
    const int n = blockIdx.x;
    const int f = threadIdx.x;
    const int p0 = indptr[n], p1 = indptr[n + 1];
    float m = -INFINITY, den = 0.f, num = 0.f;
    for (int p = p0; p < p1; ++p) {
        const int e = eidx[p];
        const int s = srcs[e];
        float msg = fmaxf(b2f(h16[(size_t)s * F + f]) + b2f(eb16[(size_t)e * F + f]), 0.f) + 1e-7f;
        float nm  = fmaxf(m, msg);
        float scl = __expf(m - nm);
        float pv  = __expf(msg - nm);
        den = den * scl + pv;
        num = num * scl + pv * msg;
        m = nm;
    }
    float o = num / (den + 1e-16f) + b2f(hd16[(size_t)n * F + f]);
    out16[(size_t)n * F + f] = f2b(o);
}

// ------------------- weight convert+transpose: Wt[f][k] = bf16(W[k][f]) ----
__global__ void k_wt(const float* __restrict__ W, u16* __restrict__ Wt, int K, int F) {
    int i = blockIdx.x * 256 + threadIdx.x;
    if (i < K * F) {
        int fcol = i / K, k = i - fcol * K;
        Wt[i] = f2b(W[(size_t)k * F + fcol]);
    }
}

// ----------------------------- BatchNorm ----------------------------------
__global__ __launch_bounds__(256) void k_bnstats(
    const u16* __restrict__ h1, float* __restrict__ sums, float* __restrict__ sumsq,
    int Nr, int C)
{
    const int c = blockIdx.x * 64 + (threadIdx.x & 63);
    float s = 0.f, s2 = 0.f;
    for (int r = blockIdx.y * 4 + (threadIdx.x >> 6); r < Nr; r += gridDim.y * 4) {
        float v = b2f(h1[(size_t)r * C + c]);
        s += v; s2 += v * v;
    }
    __shared__ float ls[256], ls2[256];
    ls[threadIdx.x] = s; ls2[threadIdx.x] = s2;
    __syncthreads();
    if (threadIdx.x < 64) {
        float a = ls[threadIdx.x] + ls[threadIdx.x + 64] + ls[threadIdx.x + 128] + ls[threadIdx.x + 192];
        float b = ls2[threadIdx.x] + ls2[threadIdx.x + 64] + ls2[threadIdx.x + 128] + ls2[threadIdx.x + 192];
        unsafeAtomicAdd(&sums[c], a);
        unsafeAtomicAdd(&sumsq[c], b);
    }
}

__global__ void k_bnfinal(const float* __restrict__ sums, const float* __restrict__ sumsq,
                          const float* __restrict__ g, const float* __restrict__ bt,
                          float* __restrict__ scale, float* __restrict__ shift,
                          int C, float invN)
{
    int c = blockIdx.x * 256 + threadIdx.x;
    if (c < C) {
        float mu  = sums[c] * invN;
        float var = sumsq[c] * invN - mu * mu;
        float s   = g[c] * rsqrtf(var + 1e-5f);
        scale[c] = s;
        shift[c] = bt[c] - mu * s;
    }
}

__global__ void k_bnrelu(u16* __restrict__ h1, const float* __restrict__ scale,
                         const float* __restrict__ shift, int total, int cmask)
{
    int i = (blockIdx.x * 256 + threadIdx.x) << 3;
    if (i < total) {
        sv8 v = *(sv8*)&h1[i];
        int c0 = i & cmask;
        #pragma unroll
        for (int j = 0; j < 8; ++j) {
            float x = b2f((u16)v[j]);
            float y = fmaxf(x * scale[c0 + j] + shift[c0 + j], 0.f);
            v[j] = (short)f2b(y);
        }
        *(sv8*)&h1[i] = v;
    }
}

// ---------------------------------------------------------------------------
extern "C" void kernel_launch(void* const* d_in, const int* in_sizes, int n_in,
                              void* d_out, int out_size, void* d_ws, size_t ws_size,
                              hipStream_t stream)
{
    const int IN = 128, HID = 256, OUT = 128, ED = 64;
    const int N = in_sizes[0] / IN;
    const int E = in_sizes[1] / 2;

    const float* x   = (const float*)d_in[0];
    const int*   src = (const int*)d_in[1];
    const int*   dst = src + E;
    const float* ea  = (const float*)d_in[2];
    auto F32 = [&](int i) { return (const float*)d_in[i]; };
    const float *Wsrc1 = F32(3),  *bsrc1 = F32(4),  *Wdst1 = F32(5),  *bdst1 = F32(6),
                *We1   = F32(7),  *be1   = F32(8),  *W11   = F32(9),  *b11   = F32(10),
                *g1    = F32(11), *bt1   = F32(12), *W21   = F32(13), *b21   = F32(14);
    const float *Wsrc2 = F32(15), *bsrc2 = F32(16), *Wdst2 = F32(17), *bdst2 = F32(18),
                *We2   = F32(19), *be2   = F32(20), *W12   = F32(21), *b12   = F32(22),
                *g2    = F32(23), *bt2   = F32(24), *W22   = F32(25), *b22   = F32(26);

    char* wp = (char*)d_ws;
    auto carve = [&](size_t bytes) -> void* {
        void* r = (void*)wp; wp += (bytes + 255) & ~(size_t)255; return r;
    };
    u16* wsrc1t = (u16*)carve((size_t)HID * IN * 2);
    u16* wdst1t = (u16*)carve((size_t)HID * IN * 2);
    u16* we1t   = (u16*)carve((size_t)HID * ED * 2);
    u16* w11t   = (u16*)carve((size_t)(2 * HID) * HID * 2);
    u16* w21t   = (u16*)carve((size_t)HID * (2 * HID) * 2);
    u16* wsrc2t = (u16*)carve((size_t)OUT * HID * 2);
    u16* wdst2t = (u16*)carve((size_t)OUT * HID * 2);
    u16* we2t   = (u16*)carve((size_t)OUT * ED * 2);
    u16* w12t   = (u16*)carve((size_t)(2 * OUT) * OUT * 2);
    u16* w22t   = (u16*)carve((size_t)OUT * (2 * OUT) * 2);
    int* counts  = (int*)carve((size_t)N * 4);
    int* indptr  = (int*)carve((size_t)(N + 1) * 4);
    int* cursors = (int*)carve((size_t)N * 4);
    int* eidx    = (int*)carve((size_t)E * 4);
    u16* h16   = (u16*)carve((size_t)N * HID * 2);
    u16* hd16  = (u16*)carve((size_t)N * HID * 2);
    u16* out16 = (u16*)carve((size_t)N * HID * 2);
    u16* x2    = (u16*)carve((size_t)N * HID * 2);
    u16* h1    = (u16*)carve((size_t)N * (2 * HID) * 2);
    u16* eb16  = (u16*)carve((size_t)E * HID * 2);
    float* stats1 = (float*)carve(2 * (size_t)(2 * HID) * 4);
    float* ss1    = (float*)carve(2 * (size_t)(2 * HID) * 4);
    float* stats2 = (float*)carve(2 * (size_t)(2 * OUT) * 4);
    float* ss2    = (float*)carve(2 * (size_t)(2 * OUT) * 4);

    // CSR by destination
    hipMemsetAsync(counts, 0, (size_t)N * 4, stream);
    k_hist<<<dim3((E + 255) / 256), dim3(256), 0, stream>>>(dst, counts, E);
    k_scan<<<dim3(1), dim3(1024), 0, stream>>>(counts, indptr, cursors, N);
    k_scatter<<<dim3((E + 255) / 256), dim3(256), 0, stream>>>(dst, cursors, eidx, E);

    // weight conversions (transpose to [F][K] bf16)
    auto wt = [&](const float* W, u16* Wt, int K, int F) {
        k_wt<<<dim3((K * F + 255) / 256), dim3(256), 0, stream>>>(W, Wt, K, F);
    };
    wt(Wsrc1, wsrc1t, IN, HID);  wt(Wdst1, wdst1t, IN, HID);
    wt(We1,   we1t,   ED, HID);  wt(W11,   w11t,   HID, 2 * HID);
    wt(W21,   w21t,   2 * HID, HID);
    wt(Wsrc2, wsrc2t, HID, OUT); wt(Wdst2, wdst2t, HID, OUT);
    wt(We2,   we2t,   ED, OUT);  wt(W12,   w12t,   OUT, 2 * OUT);
    wt(W22,   w22t,   2 * OUT, OUT);

    auto gemm = [&](const void* A, bool af32, const u16* Wt, const float* bias,
                    void* C, bool of32, bool relu, int M, int K, int F) {
        dim3 g((M + 63) / 64, F / 64), b(256);
        if (af32)      k_gemm<true,  false, false><<<g, b, 0, stream>>>(A, Wt, bias, C, M, K, F);
        else if (of32) k_gemm<false, true,  false><<<g, b, 0, stream>>>(A, Wt, bias, C, M, K, F);
        else if (relu) k_gemm<false, false, true ><<<g, b, 0, stream>>>(A, Wt, bias, C, M, K, F);
        else           k_gemm<false, false, false><<<g, b, 0, stream>>>(A, Wt, bias, C, M, K, F);
    };

    // ---------------- Layer 1 (IN=128 -> HID=256) ----------------
    gemm(x,  true, wsrc1t, bsrc1, h16,  false, false, N, IN, HID);
    gemm(x,  true, wdst1t, bdst1, hd16, false, false, N, IN, HID);
    gemm(ea, true, we1t,   be1,   eb16, false, false, E, ED, HID);
    k_agg<256><<<dim3(N), dim3(256), 0, stream>>>(h16, eb16, hd16, src, indptr, eidx, out16);
    gemm(out16, false, w11t, b11, h1, false, false, N, HID, 2 * HID);
    hipMemsetAsync(stats1, 0, 2 * (size_t)(2 * HID) * 4, stream);
    k_bnstats<<<dim3((2 * HID) / 64, 64), dim3(256), 0, stream>>>(h1, stats1, stats1 + 2 * HID, N, 2 * HID);
    k_bnfinal<<<dim3((2 * HID + 255) / 256), dim3(256), 0, stream>>>(
        stats1, stats1 + 2 * HID, g1, bt1, ss1, ss1 + 2 * HID, 2 * HID, 1.f / N);
    k_bnrelu<<<dim3(((size_t)N * (2 * HID) / 8 + 255) / 256), dim3(256), 0, stream>>>(
        h1, ss1, ss1 + 2 * HID, N * (2 * HID), 2 * HID - 1);
    gemm(h1, false, w21t, b21, x2, false, true, N, 2 * HID, HID);   // + inter-layer relu

    // ---------------- Layer 2 (HID=256 -> OUT=128) ----------------
    gemm(x2, false, wsrc2t, bsrc2, h16,  false, false, N, HID, OUT);
    gemm(x2, false, wdst2t, bdst2, hd16, false, false, N, HID, OUT);
    gemm(ea, true,  we2t,   be2,   eb16, false, false, E, ED, OUT);
    k_agg<128><<<dim3(N), dim3(128), 0, stream>>>(h16, eb16, hd16, src, indptr, eidx, out16);
    gemm(out16, false, w12t, b12, h1, false, false, N, OUT, 2 * OUT);
    hipMemsetAsync(stats2, 0, 2 * (size_t)(2 * OUT) * 4, stream);
    k_bnstats<<<dim3((2 * OUT) / 64, 64), dim3(256), 0, stream>>>(h1, stats2, stats2 + 2 * OUT, N, 2 * OUT);
    k_bnfinal<<<dim3(1), dim3(256), 0, stream>>>(
        stats2, stats2 + 2 * OUT, g2, bt2, ss2, ss2 + 2 * OUT, 2 * OUT, 1.f / N);
    k_bnrelu<<<dim3(((size_t)N * (2 * OUT) / 8 + 255) / 256), dim3(256), 0, stream>>>(
        h1, ss2, ss2 + 2 * OUT, N * (2 * OUT), 2 * OUT - 1);
    gemm(h1, false, w22t, b22, d_out, true, false, N, 2 * OUT, OUT);
}

// Round 2
// 898.897 us; speedup vs baseline: 1.1633x; 1.1633x over previous
//
#include <hip/hip_runtime.h>

typedef unsigned short u16;
typedef __attribute__((ext_vector_type(8))) short sv8;   // 8 bf16 in 4 VGPRs
typedef __attribute__((ext_vector_type(4))) float fv4;   // MFMA accumulator
typedef __attribute__((ext_vector_type(4))) unsigned short us4;
typedef __attribute__((ext_vector_type(2))) unsigned short us2;

__device__ __forceinline__ u16 f2b(float x) {
    union { float f; unsigned u; } a; a.f = x;
    unsigned r = a.u + 0x7FFFu + ((a.u >> 16) & 1u);
    return (u16)(r >> 16);
}
__device__ __forceinline__ float b2f(u16 h) {
    union { unsigned u; float f; } a; a.u = ((unsigned)h) << 16;
    return a.f;
}

// ---------------------------------------------------------------------------
// GEMM: C[M,F] = A[M,K] @ W[K,F] + bias, W pre-transposed as Wt[F][K] (bf16).
// A is f32 (AF32) or bf16. EPI: 0 = bias only, 1 = bias+relu (bf16 out),
// 3 = bias, f32 out, 2 = GENConv message epilogue:
//     A rows gathered via perm[], out = relu(acc + bias + h[srcp[row]]) + 1e-7
// Block: 256 thr = 4 waves; tile 64x64, BK=32; wave w does rows w*16..+15.
// mfma_f32_16x16x32_bf16 layouts (measured, learn_hip m89/m91):
//   A: lane holds row (l&15), k = (l>>4)*8 + j
//   B: lane holds col (l&15), k = (l>>4)*8 + j
//   D: col = l&15, row = (l>>4)*4 + r
// ---------------------------------------------------------------------------
template<bool AF32, int EPI>
__global__ __launch_bounds__(256) void k_gemm(
    const void* __restrict__ Aptr, const u16* __restrict__ Wt,
    const float* __restrict__ bias, void* __restrict__ Cptr,
    int M, int K, int F,
    const int* __restrict__ perm, const int* __restrict__ srcp,
    const u16* __restrict__ hg)
{
    __shared__ u16 As[64][40];   // padded: stride 80B -> ~2-way bank alias (free)
    __shared__ u16 Bs[64][40];
    const int t = threadIdx.x;
    const int w = t >> 6;
    const int l = t & 63;
    const int m0 = blockIdx.x * 64;
    const int n0 = blockIdx.y * 64;
    const int arow = t >> 2;            // 0..63
    const int acol = (t & 3) << 3;      // 0,8,16,24

    const int gr = m0 + arow;
    int aridx = gr;
    if constexpr (EPI == 2) { if (gr < M) aridx = perm[gr]; }

    fv4 acc[4] = {};

    for (int k0 = 0; k0 < K; k0 += 32) {
        sv8 av = {};
        if (gr < M) {
            if constexpr (AF32) {
                const fv4* Ap = (const fv4*)((const float*)Aptr + (size_t)aridx * K + (k0 + acol));
                fv4 u = Ap[0], v = Ap[1];
                #pragma unroll
                for (int j = 0; j < 4; ++j) {
                    av[j]     = (short)f2b(u[j]);
                    av[j + 4] = (short)f2b(v[j]);
                }
            } else {
                av = *(const sv8*)((const u16*)Aptr + (size_t)aridx * K + (k0 + acol));
            }
        }
        *(sv8*)&As[arow][acol] = av;
        *(sv8*)&Bs[arow][acol] = *(const sv8*)(Wt + (size_t)(n0 + arow) * K + (k0 + acol));
        __syncthreads();

        sv8 a = *(const sv8*)&As[(w << 4) + (l & 15)][(l >> 4) << 3];
        #pragma unroll
        for (int ct = 0; ct < 4; ++ct) {
            sv8 b = *(const sv8*)&Bs[(ct << 4) + (l & 15)][(l >> 4) << 3];
            acc[ct] = __builtin_amdgcn_mfma_f32_16x16x32_bf16(a, b, acc[ct], 0, 0, 0);
        }
        __syncthreads();
    }

    const int r0 = m0 + (w << 4) + ((l >> 4) << 2);
    if constexpr (EPI == 2) {
        #pragma unroll
        for (int r = 0; r < 4; ++r) {
            const int row = r0 + r;
            if (row < M) {
                const u16* hrow = hg + (size_t)srcp[row] * F;
                #pragma unroll
                for (int ct = 0; ct < 4; ++ct) {
                    const int col = n0 + (ct << 4) + (l & 15);
                    float v = acc[ct][r] + bias[col] + b2f(hrow[col]);
                    v = fmaxf(v, 0.f) + 1e-7f;
                    ((u16*)Cptr)[(size_t)row * F + col] = f2b(v);
                }
            }
        }
    } else {
        #pragma unroll
        for (int ct = 0; ct < 4; ++ct) {
            const int col = n0 + (ct << 4) + (l & 15);
            const float bv = bias[col];
            #pragma unroll
            for (int r = 0; r < 4; ++r) {
                const int row = r0 + r;
                if (row < M) {
                    float v = acc[ct][r] + bv;
                    if constexpr (EPI == 1) v = fmaxf(v, 0.f);
                    if constexpr (EPI == 3) ((float*)Cptr)[(size_t)row * F + col] = v;
                    else                    ((u16*)Cptr)[(size_t)row * F + col] = f2b(v);
                }
            }
        }
    }
}

// --------------------------- CSR build (by dst) ----------------------------
__global__ void k_hist(const int* __restrict__ dst, int* __restrict__ counts, int E) {
    int i = blockIdx.x * 256 + threadIdx.x;
    if (i < E) atomicAdd(&counts[dst[i]], 1);
}

__global__ __launch_bounds__(1024) void k_scan(
    const int* __restrict__ counts, int* __restrict__ indptr,
    int* __restrict__ cursors, int n)
{
    __shared__ int sm[1024];
    const int t = threadIdx.x;
    const int CH = (n + 1023) >> 10;
    const int base = t * CH;
    int s = 0;
    for (int i = 0; i < CH; ++i) { int idx = base + i; if (idx < n) s += counts[idx]; }
    sm[t] = s;
    __syncthreads();
    for (int off = 1; off < 1024; off <<= 1) {
        int v = (t >= off) ? sm[t - off] : 0;
        __syncthreads();
        sm[t] += v;
        __syncthreads();
    }
    int run = sm[t] - s;   // exclusive prefix of this thread's chunk
    for (int i = 0; i < CH; ++i) {
        int idx = base + i;
        if (idx < n) { indptr[idx] = run; cursors[idx] = run; run += counts[idx]; }
    }
    if (t == 1023) indptr[n] = sm[1023];
}

__global__ void k_scatter(const int* __restrict__ dst, const int* __restrict__ src,
                          int* __restrict__ cursors, int* __restrict__ perm,
                          int* __restrict__ srcp, int E) {
    int i = blockIdx.x * 256 + threadIdx.x;
    if (i < E) {
        int p = atomicAdd(&cursors[dst[i]], 1);
        perm[p] = i;
        srcp[p] = src[i];
    }
}

// ------------- softmax aggregation (msg rows contiguous in CSR order) ------
// No max subtraction needed: msg = relu(.)+1e-7 is O(10) max, exp() safe in
// f32 (overflow at 88); reference's +1e-16 on den is negligible vs den>=1.
// One wave per node, 4 nodes per block, VPT features per lane.
template<int F, int VPT>
__global__ __launch_bounds__(256) void k_agg(
    const u16* __restrict__ msg, const u16* __restrict__ hd16,
    const int* __restrict__ indptr, u16* __restrict__ out16, int N)
{
    const int nid = blockIdx.x * 4 + (threadIdx.x >> 6);
    if (nid >= N) return;
    const int c0 = (threadIdx.x & 63) * VPT;   // F/VPT == 64 lanes used
    const int p0 = indptr[nid], p1 = indptr[nid + 1];
    float den[VPT] = {}, num[VPT] = {};
    for (int p = p0; p < p1; ++p) {
        const u16* rp = msg + (size_t)p * F + c0;
        u16 vals[VPT];
        if constexpr (VPT == 4) *(us4*)vals = *(const us4*)rp;
        else                    *(us2*)vals = *(const us2*)rp;
        #pragma unroll
        for (int j = 0; j < VPT; ++j) {
            float x = b2f(vals[j]);
            float e = __expf(x);
            den[j] += e;
            num[j] += e * x;
        }
    }
    #pragma unroll
    for (int j = 0; j < VPT; ++j) {
        float o = num[j] / (den[j] + 1e-16f) + b2f(hd16[(size_t)nid * F + c0 + j]);
        out16[(size_t)nid * F + c0 + j] = f2b(o);
    }
}

// ------------------- weight convert+transpose: Wt[f][k] = bf16(W[k][f]) ----
__global__ void k_wt(const float* __restrict__ W, u16* __restrict__ Wt, int K, int F) {
    int i = blockIdx.x * 256 + threadIdx.x;
    if (i < K * F) {
        int fcol = i / K, k = i - fcol * K;
        Wt[i] = f2b(W[(size_t)k * F + fcol]);
    }
}

// ----------------------------- BatchNorm ----------------------------------
__global__ __launch_bounds__(256) void k_bnstats(
    const u16* __restrict__ h1, float* __restrict__ sums, float* __restrict__ sumsq,
    int Nr, int C)
{
    const int c = blockIdx.x * 64 + (threadIdx.x & 63);
    float s = 0.f, s2 = 0.f;
    for (int r = blockIdx.y * 4 + (threadIdx.x >> 6); r < Nr; r += gridDim.y * 4) {
        float v = b2f(h1[(size_t)r * C + c]);
        s += v; s2 += v * v;
    }
    __shared__ float ls[256], ls2[256];
    ls[threadIdx.x] = s; ls2[threadIdx.x] = s2;
    __syncthreads();
    if (threadIdx.x < 64) {
        float a = ls[threadIdx.x] + ls[threadIdx.x + 64] + ls[threadIdx.x + 128] + ls[threadIdx.x + 192];
        float b = ls2[threadIdx.x] + ls2[threadIdx.x + 64] + ls2[threadIdx.x + 128] + ls2[threadIdx.x + 192];
        unsafeAtomicAdd(&sums[c], a);
        unsafeAtomicAdd(&sumsq[c], b);
    }
}

__global__ void k_bnfinal(const float* __restrict__ sums, const float* __restrict__ sumsq,
                          const float* __restrict__ g, const float* __restrict__ bt,
                          float* __restrict__ scale, float* __restrict__ shift,
                          int C, float invN)
{
    int c = blockIdx.x * 256 + threadIdx.x;
    if (c < C) {
        float mu  = sums[c] * invN;
        float var = sumsq[c] * invN - mu * mu;
        float s   = g[c] * rsqrtf(var + 1e-5f);
        scale[c] = s;
        shift[c] = bt[c] - mu * s;
    }
}

__global__ void k_bnrelu(u16* __restrict__ h1, const float* __restrict__ scale,
                         const float* __restrict__ shift, int total, int cmask)
{
    int i = (blockIdx.x * 256 + threadIdx.x) << 3;
    if (i < total) {
        sv8 v = *(sv8*)&h1[i];
        int c0 = i & cmask;
        #pragma unroll
        for (int j = 0; j < 8; ++j) {
            float x = b2f((u16)v[j]);
            float y = fmaxf(x * scale[c0 + j] + shift[c0 + j], 0.f);
            v[j] = (short)f2b(y);
        }
        *(sv8*)&h1[i] = v;
    }
}

// ---------------------------------------------------------------------------
extern "C" void kernel_launch(void* const* d_in, const int* in_sizes, int n_in,
                              void* d_out, int out_size, void* d_ws, size_t ws_size,
                              hipStream_t stream)
{
    const int IN = 128, HID = 256, OUT = 128, ED = 64;
    const int N = in_sizes[0] / IN;
    const int E = in_sizes[1] / 2;

    const float* x   = (const float*)d_in[0];
    const int*   src = (const int*)d_in[1];
    const int*   dst = src + E;
    const float* ea  = (const float*)d_in[2];
    auto F32 = [&](int i) { return (const float*)d_in[i]; };
    const float *Wsrc1 = F32(3),  *bsrc1 = F32(4),  *Wdst1 = F32(5),  *bdst1 = F32(6),
                *We1   = F32(7),  *be1   = F32(8),  *W11   = F32(9),  *b11   = F32(10),
                *g1    = F32(11), *bt1   = F32(12), *W21   = F32(13), *b21   = F32(14);
    const float *Wsrc2 = F32(15), *bsrc2 = F32(16), *Wdst2 = F32(17), *bdst2 = F32(18),
                *We2   = F32(19), *be2   = F32(20), *W12   = F32(21), *b12   = F32(22),
                *g2    = F32(23), *bt2   = F32(24), *W22   = F32(25), *b22   = F32(26);

    char* wp = (char*)d_ws;
    auto carve = [&](size_t bytes) -> void* {
        void* r = (void*)wp; wp += (bytes + 255) & ~(size_t)255; return r;
    };
    u16* wsrc1t = (u16*)carve((size_t)HID * IN * 2);
    u16* wdst1t = (u16*)carve((size_t)HID * IN * 2);
    u16* we1t   = (u16*)carve((size_t)HID * ED * 2);
    u16* w11t   = (u16*)carve((size_t)(2 * HID) * HID * 2);
    u16* w21t   = (u16*)carve((size_t)HID * (2 * HID) * 2);
    u16* wsrc2t = (u16*)carve((size_t)OUT * HID * 2);
    u16* wdst2t = (u16*)carve((size_t)OUT * HID * 2);
    u16* we2t   = (u16*)carve((size_t)OUT * ED * 2);
    u16* w12t   = (u16*)carve((size_t)(2 * OUT) * OUT * 2);
    u16* w22t   = (u16*)carve((size_t)OUT * (2 * OUT) * 2);
    int* counts  = (int*)carve((size_t)N * 4);
    int* indptr  = (int*)carve((size_t)(N + 1) * 4);
    int* cursors = (int*)carve((size_t)N * 4);
    int* perm    = (int*)carve((size_t)E * 4);
    int* srcp    = (int*)carve((size_t)E * 4);
    u16* h16   = (u16*)carve((size_t)N * HID * 2);
    u16* hd16  = (u16*)carve((size_t)N * HID * 2);
    u16* out16 = (u16*)carve((size_t)N * HID * 2);
    u16* x2    = (u16*)carve((size_t)N * HID * 2);
    u16* h1    = (u16*)carve((size_t)N * (2 * HID) * 2);
    u16* msgb  = (u16*)carve((size_t)E * HID * 2);
    float* stats1 = (float*)carve(2 * (size_t)(2 * HID) * 4);
    float* ss1    = (float*)carve(2 * (size_t)(2 * HID) * 4);
    float* stats2 = (float*)carve(2 * (size_t)(2 * OUT) * 4);
    float* ss2    = (float*)carve(2 * (size_t)(2 * OUT) * 4);

    // CSR by destination (perm[p] = edge id, srcp[p] = src node of that edge)
    hipMemsetAsync(counts, 0, (size_t)N * 4, stream);
    k_hist<<<dim3((E + 255) / 256), dim3(256), 0, stream>>>(dst, counts, E);
    k_scan<<<dim3(1), dim3(1024), 0, stream>>>(counts, indptr, cursors, N);
    k_scatter<<<dim3((E + 255) / 256), dim3(256), 0, stream>>>(dst, src, cursors, perm, srcp, E);

    // weight conversions (transpose to [F][K] bf16)
    auto wt = [&](const float* W, u16* Wt, int K, int F) {
        k_wt<<<dim3((K * F + 255) / 256), dim3(256), 0, stream>>>(W, Wt, K, F);
    };
    wt(Wsrc1, wsrc1t, IN, HID);  wt(Wdst1, wdst1t, IN, HID);
    wt(We1,   we1t,   ED, HID);  wt(W11,   w11t,   HID, 2 * HID);
    wt(W21,   w21t,   2 * HID, HID);
    wt(Wsrc2, wsrc2t, HID, OUT); wt(Wdst2, wdst2t, HID, OUT);
    wt(We2,   we2t,   ED, OUT);  wt(W12,   w12t,   OUT, 2 * OUT);
    wt(W22,   w22t,   2 * OUT, OUT);

    auto gemm = [&](const void* A, const u16* Wt, const float* bias, void* C,
                    int epi, bool af32, int M, int K, int F,
                    const int* pm = nullptr, const int* sp = nullptr,
                    const u16* hgat = nullptr) {
        dim3 g((M + 63) / 64, F / 64), b(256);
        if (af32) {
            if (epi == 2)      k_gemm<true, 2><<<g, b, 0, stream>>>(A, Wt, bias, C, M, K, F, pm, sp, hgat);
            else               k_gemm<true, 0><<<g, b, 0, stream>>>(A, Wt, bias, C, M, K, F, nullptr, nullptr, nullptr);
        } else {
            if (epi == 0)      k_gemm<false, 0><<<g, b, 0, stream>>>(A, Wt, bias, C, M, K, F, nullptr, nullptr, nullptr);
            else if (epi == 1) k_gemm<false, 1><<<g, b, 0, stream>>>(A, Wt, bias, C, M, K, F, nullptr, nullptr, nullptr);
            else               k_gemm<false, 3><<<g, b, 0, stream>>>(A, Wt, bias, C, M, K, F, nullptr, nullptr, nullptr);
        }
    };

    // ---------------- Layer 1 (IN=128 -> HID=256) ----------------
    gemm(x,  wsrc1t, bsrc1, h16,  0, true, N, IN, HID);          // lin_src
    gemm(x,  wdst1t, bdst1, hd16, 0, true, N, IN, HID);          // lin_dst
    gemm(ea, we1t,   be1,   msgb, 2, true, E, ED, HID, perm, srcp, h16);  // msg, CSR order
    k_agg<256, 4><<<dim3((N + 3) / 4), dim3(256), 0, stream>>>(msgb, hd16, indptr, out16, N);
    gemm(out16, w11t, b11, h1, 0, false, N, HID, 2 * HID);
    hipMemsetAsync(stats1, 0, 2 * (size_t)(2 * HID) * 4, stream);
    k_bnstats<<<dim3((2 * HID) / 64, 64), dim3(256), 0, stream>>>(h1, stats1, stats1 + 2 * HID, N, 2 * HID);
    k_bnfinal<<<dim3((2 * HID + 255) / 256), dim3(256), 0, stream>>>(
        stats1, stats1 + 2 * HID, g1, bt1, ss1, ss1 + 2 * HID, 2 * HID, 1.f / N);
    k_bnrelu<<<dim3(((size_t)N * (2 * HID) / 8 + 255) / 256), dim3(256), 0, stream>>>(
        h1, ss1, ss1 + 2 * HID, N * (2 * HID), 2 * HID - 1);
    gemm(h1, w21t, b21, x2, 1, false, N, 2 * HID, HID);          // + inter-layer relu

    // ---------------- Layer 2 (HID=256 -> OUT=128) ----------------
    gemm(x2, wsrc2t, bsrc2, h16,  0, false, N, HID, OUT);
    gemm(x2, wdst2t, bdst2, hd16, 0, false, N, HID, OUT);
    gemm(ea, we2t,   be2,   msgb, 2, true, E, ED, OUT, perm, srcp, h16);
    k_agg<128, 2><<<dim3((N + 3) / 4), dim3(256), 0, stream>>>(msgb, hd16, indptr, out16, N);
    gemm(out16, w12t, b12, h1, 0, false, N, OUT, 2 * OUT);
    hipMemsetAsync(stats2, 0, 2 * (size_t)(2 * OUT) * 4, stream);
    k_bnstats<<<dim3((2 * OUT) / 64, 64), dim3(256), 0, stream>>>(h1, stats2, stats2 + 2 * OUT, N, 2 * OUT);
    k_bnfinal<<<dim3(1), dim3(256), 0, stream>>>(
        stats2, stats2 + 2 * OUT, g2, bt2, ss2, ss2 + 2 * OUT, 2 * OUT, 1.f / N);
    k_bnrelu<<<dim3(((size_t)N * (2 * OUT) / 8 + 255) / 256), dim3(256), 0, stream>>>(
        h1, ss2, ss2 + 2 * OUT, N * (2 * OUT), 2 * OUT - 1);
    gemm(h1, w22t, b22, d_out, 3, false, N, 2 * OUT, OUT);
}